// Round 5
// baseline (210.178 us; speedup 1.0000x reference)
//
#include <hip/hip_runtime.h>
#include <hip/hip_bf16.h>

// Problem constants (fixed by reference)
#define N_NODES   16384
#define DEG       16
#define EDGES     262144          // N_NODES*DEG
#define HC        256             // HEADS*OUT_C
#define KDIM      16384           // 64 nodes * 256 feat
#define NEG_SLOPE 0.2f

typedef __attribute__((ext_vector_type(8))) short short8;   // 8 bf16
typedef __attribute__((ext_vector_type(4))) float floatx4;

static __device__ __forceinline__ unsigned short f2bf(float f) {
    union { __hip_bfloat16 h; unsigned short u; } c;
    c.h = __float2bfloat16(f);          // RNE
    return c.u;
}
static __device__ __forceinline__ unsigned int packbf2(float lo, float hi) {
    union { __hip_bfloat162 h2; unsigned int u; } c;
    c.h2 = __float22bfloat162_rn(make_float2(lo, hi));   // v_cvt_pk_bf16_f32
    return c.u;
}

// ---- mean(edge_attr) partial sums: 256 blocks x 1024 rows -----------------
__global__ __launch_bounds__(256) void k_ea_part(const float* __restrict__ ea,
                                                 float* __restrict__ part) {
    __shared__ float s[256];
    int b = blockIdx.x, t = threadIdx.x;
    int col = t & 15, r0 = t >> 4;
    const float* base = ea + (size_t)b * 1024 * 16;
    float acc = 0.f;
    for (int r = r0; r < 1024; r += 16) acc += base[r * 16 + col];
    s[t] = acc; __syncthreads();
    for (int off = 128; off >= 16; off >>= 1) {
        if (t < off) s[t] += s[t + off];
        __syncthreads();
    }
    if (t < 16) part[b * 16 + t] = s[t];
}

// ---- finish mean + ee_self = mean_ea @ W_e ---------------------------------
__global__ __launch_bounds__(256) void k_ea_finish(const float* __restrict__ part,
                                                   const float* __restrict__ We,
                                                   float* __restrict__ eeself) {
    __shared__ float mean[16];
    int t = threadIdx.x;
    if (t < 16) {
        float a = 0.f;
        for (int b = 0; b < 256; ++b) a += part[b * 16 + t];
        mean[t] = a * (1.f / (float)EDGES);
    }
    __syncthreads();
    float acc = 0.f;
    #pragma unroll
    for (int d = 0; d < 16; ++d) acc += mean[d] * We[d * 256 + t];
    eeself[t] = acc;
}

// ---- xl|xr via MFMA: (16384 x 128) @ (128 x 512) ---------------------------
__global__ __launch_bounds__(256) void k_xlr2(const float* __restrict__ x,
                                              const float* __restrict__ Wl,
                                              const float* __restrict__ Wr,
                                              float* __restrict__ xl,
                                              float* __restrict__ xr) {
    __shared__ unsigned short As[64][40];   // [row][k] bf16
    __shared__ unsigned int   Bs[128][18];  // [col][kpair]
    unsigned int* As32 = (unsigned int*)&As[0][0];

    int t = threadIdx.x;
    int wave = t >> 6, lane = t & 63;
    int l15 = lane & 15, lk = lane >> 4;
    int wm = wave >> 1, wn = wave & 1;
    int m0 = blockIdx.x * 64;
    int n0 = blockIdx.y * 128;
    const float* Wsel = (n0 < 256) ? Wl : Wr;
    int bc = n0 & 255;

    floatx4 acc[2][4];
    #pragma unroll
    for (int i = 0; i < 2; ++i)
        #pragma unroll
        for (int j = 0; j < 4; ++j)
            acc[i][j] = (floatx4)(0.f);

    int ar = t >> 2, ac = t & 3;
    int bkp = t >> 4, bcc = t & 15;

    for (int k0 = 0; k0 < 128; k0 += 32) {
        __syncthreads();
        {   // stage A: x[m0+r][k0 + ac*8 .. +7] -> bf16
            const float* gp = x + (size_t)(m0 + ar) * 128 + k0 + ac * 8;
            float4 v0 = *(const float4*)gp;
            float4 v1 = *(const float4*)(gp + 4);
            As32[ar * 20 + ac * 4 + 0] = packbf2(v0.x, v0.y);
            As32[ar * 20 + ac * 4 + 1] = packbf2(v0.z, v0.w);
            As32[ar * 20 + ac * 4 + 2] = packbf2(v1.x, v1.y);
            As32[ar * 20 + ac * 4 + 3] = packbf2(v1.z, v1.w);
        }
        {   // stage B
            const float* wp = Wsel + (size_t)(k0 + 2 * bkp) * 256 + bc + bcc * 8;
            float4 r0a = *(const float4*)wp;
            float4 r0b = *(const float4*)(wp + 4);
            float4 r1a = *(const float4*)(wp + 256);
            float4 r1b = *(const float4*)(wp + 260);
            Bs[bcc * 8 + 0][bkp] = packbf2(r0a.x, r1a.x);
            Bs[bcc * 8 + 1][bkp] = packbf2(r0a.y, r1a.y);
            Bs[bcc * 8 + 2][bkp] = packbf2(r0a.z, r1a.z);
            Bs[bcc * 8 + 3][bkp] = packbf2(r0a.w, r1a.w);
            Bs[bcc * 8 + 4][bkp] = packbf2(r0b.x, r1b.x);
            Bs[bcc * 8 + 5][bkp] = packbf2(r0b.y, r1b.y);
            Bs[bcc * 8 + 6][bkp] = packbf2(r0b.z, r1b.z);
            Bs[bcc * 8 + 7][bkp] = packbf2(r0b.w, r1b.w);
        }
        __syncthreads();
        short8 a[2], b[4];
        #pragma unroll
        for (int mi = 0; mi < 2; ++mi)
            a[mi] = *(const short8*)&As[wm * 32 + mi * 16 + l15][lk * 8];
        #pragma unroll
        for (int ni = 0; ni < 4; ++ni) {
            int nr = wn * 64 + ni * 16 + l15;
            union { uint2 u[2]; short8 v; } bb;
            bb.u[0] = *(const uint2*)&Bs[nr][lk * 4];
            bb.u[1] = *(const uint2*)&Bs[nr][lk * 4 + 2];
            b[ni] = bb.v;
        }
        #pragma unroll
        for (int mi = 0; mi < 2; ++mi)
            #pragma unroll
            for (int ni = 0; ni < 4; ++ni)
                acc[mi][ni] = __builtin_amdgcn_mfma_f32_16x16x32_bf16(a[mi], b[ni], acc[mi][ni], 0, 0, 0);
    }

    #pragma unroll
    for (int mi = 0; mi < 2; ++mi) {
        #pragma unroll
        for (int ni = 0; ni < 4; ++ni) {
            int n = n0 + wn * 64 + ni * 16 + l15;
            #pragma unroll
            for (int r = 0; r < 4; ++r) {
                int node = m0 + wm * 32 + mi * 16 + lk * 4 + r;
                if (n0 < 256) xl[(size_t)node * 256 + n]         = acc[mi][ni][r];
                else          xr[(size_t)node * 256 + (n - 256)] = acc[mi][ni][r];
            }
        }
    }
}

// ---- fused GAT attention: MFMA ee + in-layout logits + softmax + agg -------
__global__ __launch_bounds__(256) void k_attn(const int* __restrict__ ei,
                                              const float* __restrict__ ea,
                                              const float* __restrict__ eeself,
                                              const float* __restrict__ att,
                                              const float* __restrict__ We,
                                              const float* __restrict__ xl,
                                              const float* __restrict__ xr,
                                              const float* __restrict__ bg,
                                              unsigned short* __restrict__ hb) {
    __shared__ float xlS[64][65];
    __shared__ float xrS[64][65];
    __shared__ float lgS[1088];
    __shared__ int   srcS[1024];

    int t = threadIdx.x;
    int g = blockIdx.x >> 2, h = blockIdx.x & 3;
    int hc0 = h * 64;

    {   // stage xl/xr head slices
        int n = t >> 2, q4 = t & 3;
        const float* xlp = xl + ((size_t)(g * 64 + n)) * 256 + hc0 + q4 * 16;
        const float* xrp = xr + ((size_t)(g * 64 + n)) * 256 + hc0 + q4 * 16;
        #pragma unroll
        for (int i = 0; i < 4; ++i) {
            *(float4*)&xlS[n][q4 * 16 + i * 4] = *(const float4*)(xlp + i * 4);
            *(float4*)&xrS[n][q4 * 16 + i * 4] = *(const float4*)(xrp + i * 4);
        }
    }
    {   // stage local src indices
        int4 v = *(const int4*)(ei + (size_t)g * 1024 + t * 4);
        srcS[t * 4 + 0] = v.x & 63;
        srcS[t * 4 + 1] = v.y & 63;
        srcS[t * 4 + 2] = v.z & 63;
        srcS[t * 4 + 3] = v.w & 63;
    }

    int wave = t >> 6, lane = t & 63;
    int q = lane >> 4, l15 = lane & 15;

    short8 wf[4];
    float  attv[4];
    #pragma unroll
    for (int nt = 0; nt < 4; ++nt) {
        attv[nt] = att[hc0 + nt * 16 + l15];
        if (q < 2) {
            const float* wp = We + (size_t)(q * 8) * 256 + hc0 + nt * 16 + l15;
            float w0 = wp[0*256], w1 = wp[1*256], w2 = wp[2*256], w3 = wp[3*256];
            float w4 = wp[4*256], w5 = wp[5*256], w6 = wp[6*256], w7 = wp[7*256];
            union { unsigned int u[4]; short8 v; } bb;
            bb.u[0] = packbf2(w0, w1);
            bb.u[1] = packbf2(w2, w3);
            bb.u[2] = packbf2(w4, w5);
            bb.u[3] = packbf2(w6, w7);
            wf[nt] = bb.v;
        } else {
            wf[nt] = (short8)0;
        }
    }
    __syncthreads();

    for (int b = wave; b < 16; b += 4) {
        short8 af[4];
        #pragma unroll
        for (int mt = 0; mt < 4; ++mt) {
            if (q < 2) {
                const float* ep = ea + ((size_t)(g * 1024 + b * 64 + mt * 16 + l15)) * 16 + q * 8;
                float4 v0 = *(const float4*)ep;
                float4 v1 = *(const float4*)(ep + 4);
                union { unsigned int u[4]; short8 v; } bb;
                bb.u[0] = packbf2(v0.x, v0.y);
                bb.u[1] = packbf2(v0.z, v0.w);
                bb.u[2] = packbf2(v1.x, v1.y);
                bb.u[3] = packbf2(v1.z, v1.w);
                af[mt] = bb.v;
            } else {
                af[mt] = (short8)0;
            }
        }
        floatx4 acc[4][4];
        #pragma unroll
        for (int mt = 0; mt < 4; ++mt)
            #pragma unroll
            for (int nt = 0; nt < 4; ++nt)
                acc[mt][nt] = __builtin_amdgcn_mfma_f32_16x16x32_bf16(af[mt], wf[nt], (floatx4)(0.f), 0, 0, 0);

        int srcr[4][4];
        #pragma unroll
        for (int mt = 0; mt < 4; ++mt)
            #pragma unroll
            for (int r = 0; r < 4; ++r)
                srcr[mt][r] = srcS[b * 64 + mt * 16 + q * 4 + r];

        #pragma unroll
        for (int mt = 0; mt < 4; ++mt) {
            float lsum[4] = {0.f, 0.f, 0.f, 0.f};
            #pragma unroll
            for (int nt = 0; nt < 4; ++nt) {
                float xrv = xrS[b * 4 + mt][nt * 16 + l15];
                #pragma unroll
                for (int r = 0; r < 4; ++r) {
                    float f = acc[mt][nt][r] + xlS[srcr[mt][r]][nt * 16 + l15] + xrv;
                    f = fmaxf(f, NEG_SLOPE * f);
                    lsum[r] += f * attv[nt];
                }
            }
            #pragma unroll
            for (int r = 0; r < 4; ++r) {
                float v = lsum[r];
                v += __shfl_xor(v, 1);
                v += __shfl_xor(v, 2);
                v += __shfl_xor(v, 4);
                v += __shfl_xor(v, 8);
                if (l15 == 0) lgS[b * 64 + mt * 16 + q * 4 + r] = v;
            }
        }
    }

    {   // self-loop batch
        int n = wave * 16 + l15;
        float sum = 0.f;
        const float* eep = eeself + hc0 + q * 16;
        const float* ap  = att + hc0 + q * 16;
        #pragma unroll
        for (int i = 0; i < 4; ++i) {
            float4 ev = *(const float4*)(eep + i * 4);
            float4 av = *(const float4*)(ap + i * 4);
            #pragma unroll
            for (int j = 0; j < 4; ++j) {
                int c = q * 16 + i * 4 + j;
                float e = (j == 0) ? ev.x : (j == 1) ? ev.y : (j == 2) ? ev.z : ev.w;
                float a = (j == 0) ? av.x : (j == 1) ? av.y : (j == 2) ? av.z : av.w;
                float f = xlS[n][c] + xrS[n][c] + e;
                f = fmaxf(f, NEG_SLOPE * f);
                sum += f * a;
            }
        }
        sum += __shfl_xor(sum, 16);
        sum += __shfl_xor(sum, 32);
        if (q == 0) lgS[1024 + n] = sum;
    }
    __syncthreads();

    if (t < 64) {
        float lg[17];
        #pragma unroll
        for (int j = 0; j < 16; ++j) lg[j] = lgS[t * 16 + j];
        lg[16] = lgS[1024 + t];
        float m = lg[0];
        #pragma unroll
        for (int j = 1; j < 17; ++j) m = fmaxf(m, lg[j]);
        float ex[17], ssum = 0.f;
        #pragma unroll
        for (int j = 0; j < 17; ++j) { ex[j] = __expf(lg[j] - m); ssum += ex[j]; }
        float inv = 1.f / (17.f * ssum);
        #pragma unroll
        for (int j = 0; j < 16; ++j) lgS[t * 16 + j] = ex[j] * inv;
        lgS[1024 + t] = ex[16] * inv;
    }
    __syncthreads();

    {
        int c = lane;
        float bgv = bg[hc0 + c];
        for (int n = wave * 16; n < wave * 16 + 16; ++n) {
            float a0 = lgS[1024 + n] * xlS[n][c];
            float a1 = 0.f;
            #pragma unroll
            for (int j = 0; j < 16; j += 2) {
                a0 += lgS[n * 16 + j]     * xlS[srcS[n * 16 + j]][c];
                a1 += lgS[n * 16 + j + 1] * xlS[srcS[n * 16 + j + 1]][c];
            }
            float val = a0 + a1 + bgv;
            hb[((size_t)(g * 64 + n)) * 256 + hc0 + c] = f2bf(val);
        }
    }
}

// ---- big GEMM v5: counted-vmcnt pipeline, A depth-2 prefetch, swizzled -----
// (256 x 16384) bf16 @ W[16384 x 4096] -> partials[s][256][4096]
__global__ __launch_bounds__(256) void k_gemm(const unsigned short* __restrict__ hb,
                                              const float* __restrict__ W,
                                              float* __restrict__ parts) {
    // As: 3 rotating buffers, 256 rows x 32 k bf16 each, LINEAR (gload_lds dest).
    // Stored chunk position s of global 16B-chunk g at row R: s = (g + (R>>1)) & 3.
    __shared__ unsigned short As[3][256 * 32];
    __shared__ unsigned int   Bs[2][64][18];

    int t = threadIdx.x;
    int wave = t >> 6, lane = t & 63;
    int l15 = lane & 15, lk = lane >> 4;
    int n0 = blockIdx.x * 64;
    int s  = blockIdx.y;
    int kbase = s * 2048;

    floatx4 acc[4][4];
    #pragma unroll
    for (int i = 0; i < 4; ++i)
        #pragma unroll
        for (int j = 0; j < 4; ++j)
            acc[i][j] = (floatx4)(0.f);

    // A-load mapping (swizzled global source, rule 21): lane covers
    // (row16 = lane>>2, stored pos = lane&3) -> global chunk gc:
    int gc = ((lane & 3) - ((lane >> 3) & 3)) & 3;
    const unsigned short* a_src =
        hb + (size_t)(wave * 64 + (lane >> 2)) * KDIM + kbase + gc * 8;
    // A-read position for frags: p = (lk + (l15>>1)) & 3
    int ap_pos[4];
    #pragma unroll
    for (int mi = 0; mi < 4; ++mi)
        ap_pos[mi] = (wave * 64 + mi * 16 + l15) * 32 + (((lk + (l15 >> 1)) & 3) * 8);

    // B-load mapping
    int bkp = t >> 4;     // 0..15 row-pair
    int bc8 = t & 15;     // col chunk (4 cols)
    const float* b_src = W + (size_t)(kbase + 2 * bkp) * 4096 + n0 + bc8 * 4;

    #define ISSUE_A(step, buf)                                                   \
        {                                                                        \
            const unsigned short* gp_ = a_src + (size_t)(step) * 32;             \
            _Pragma("unroll")                                                    \
            for (int i_ = 0; i_ < 4; ++i_) {                                     \
                __builtin_amdgcn_global_load_lds(                                \
                    (const __attribute__((address_space(1))) unsigned int*)      \
                        (gp_ + (size_t)i_ * 16 * KDIM),                          \
                    (__attribute__((address_space(3))) unsigned int*)            \
                        &As[buf][(wave * 64 + i_ * 16) * 32],                    \
                    16, 0, 0);                                                   \
            }                                                                    \
        }
    #define ISSUE_B(step, r0, r1)                                               \
        {                                                                        \
            const float* wp_ = b_src + (size_t)(step) * 32 * 4096;               \
            r0 = *(const float4*)wp_;                                            \
            r1 = *(const float4*)(wp_ + 4096);                                   \
        }
    #define WRITE_B(buf, r0, r1)                                                 \
        {                                                                        \
            Bs[buf][bc8 * 4 + 0][bkp] = packbf2(r0.x, r1.x);                     \
            Bs[buf][bc8 * 4 + 1][bkp] = packbf2(r0.y, r1.y);                     \
            Bs[buf][bc8 * 4 + 2][bkp] = packbf2(r0.z, r1.z);                     \
            Bs[buf][bc8 * 4 + 3][bkp] = packbf2(r0.w, r1.w);                     \
        }
    #define COMPUTE(abuf, bbuf)                                                  \
        {                                                                        \
            short8 a_[4], b_[4];                                                 \
            _Pragma("unroll")                                                    \
            for (int mi = 0; mi < 4; ++mi)                                       \
                a_[mi] = *(const short8*)&As[abuf][ap_pos[mi]];                  \
            _Pragma("unroll")                                                    \
            for (int ni = 0; ni < 4; ++ni) {                                     \
                int nr_ = ni * 16 + l15;                                         \
                union { uint2 u[2]; short8 v; } bb_;                             \
                bb_.u[0] = *(const uint2*)&Bs[bbuf][nr_][lk * 4];                \
                bb_.u[1] = *(const uint2*)&Bs[bbuf][nr_][lk * 4 + 2];            \
                b_[ni] = bb_.v;                                                  \
            }                                                                    \
            _Pragma("unroll")                                                    \
            for (int mi = 0; mi < 4; ++mi)                                       \
                _Pragma("unroll")                                                \
                for (int ni = 0; ni < 4; ++ni)                                   \
                    acc[mi][ni] = __builtin_amdgcn_mfma_f32_16x16x32_bf16(       \
                        a_[mi], b_[ni], acc[mi][ni], 0, 0, 0);                   \
        }

    float4 br0, br1;
    // ---- prologue: B(0), A(0), A(1) in flight; write Bs[0] ----
    ISSUE_B(0, br0, br1);
    ISSUE_A(0, 0);
    ISSUE_A(1, 1);
    __builtin_amdgcn_sched_barrier(0);
    asm volatile("s_waitcnt vmcnt(8)" ::: "memory");   // B(0) done; A(0),A(1) fly
    __builtin_amdgcn_sched_barrier(0);
    WRITE_B(0, br0, br1);
    asm volatile("s_waitcnt lgkmcnt(0)" ::: "memory");
    __builtin_amdgcn_sched_barrier(0);
    __builtin_amdgcn_s_barrier();

    // ---- steady: t = 0..61 ----
    for (int kt = 0; kt < 62; ++kt) {
        int cur = kt & 1, nxt = cur ^ 1;
        int ar = kt % 3, aw = (kt + 2) % 3;
        ISSUE_B(kt + 1, br0, br1);
        ISSUE_A(kt + 2, aw);
        __builtin_amdgcn_sched_barrier(0);
        asm volatile("s_waitcnt vmcnt(10)" ::: "memory");  // A(kt) complete
        __builtin_amdgcn_sched_barrier(0);
        COMPUTE(ar, cur);
        __builtin_amdgcn_sched_barrier(0);
        asm volatile("s_waitcnt vmcnt(4)" ::: "memory");   // B(kt+1) ready; A(kt+2) flies
        __builtin_amdgcn_sched_barrier(0);
        WRITE_B(nxt, br0, br1);
        asm volatile("s_waitcnt lgkmcnt(0)" ::: "memory");
        __builtin_amdgcn_sched_barrier(0);
        __builtin_amdgcn_s_barrier();
    }
    // ---- peel kt = 62 ----
    {
        ISSUE_B(63, br0, br1);
        __builtin_amdgcn_sched_barrier(0);
        asm volatile("s_waitcnt vmcnt(10)" ::: "memory");
        __builtin_amdgcn_sched_barrier(0);
        COMPUTE(62 % 3, 0);
        __builtin_amdgcn_sched_barrier(0);
        asm volatile("s_waitcnt vmcnt(0)" ::: "memory");   // B(63) + A(63) done
        __builtin_amdgcn_sched_barrier(0);
        WRITE_B(1, br0, br1);
        asm volatile("s_waitcnt lgkmcnt(0)" ::: "memory");
        __builtin_amdgcn_sched_barrier(0);
        __builtin_amdgcn_s_barrier();
    }
    // ---- peel kt = 63 ----
    COMPUTE(63 % 3, 1);

    #undef ISSUE_A
    #undef ISSUE_B
    #undef WRITE_B
    #undef COMPUTE

    float* dst = parts + (size_t)s * (256 * 4096);
    #pragma unroll
    for (int mi = 0; mi < 4; ++mi) {
        #pragma unroll
        for (int ni = 0; ni < 4; ++ni) {
            int col = n0 + ni * 16 + l15;
            #pragma unroll
            for (int r = 0; r < 4; ++r) {
                int row = wave * 64 + mi * 16 + lk * 4 + r;
                dst[(size_t)row * 4096 + col] = acc[mi][ni][r];
            }
        }
    }
}

// ---- reduce partials + bias -> d_out ---------------------------------------
__global__ __launch_bounds__(256) void k_reduce(const float* __restrict__ parts,
                                                const float* __restrict__ linb,
                                                float* __restrict__ out) {
    int idx = blockIdx.x * 256 + threadIdx.x;
    float v = linb[idx & 4095];
    #pragma unroll
    for (int s = 0; s < 8; ++s) v += parts[(size_t)s * (256 * 4096) + idx];
    out[idx] = v;
}

extern "C" void kernel_launch(void* const* d_in, const int* in_sizes, int n_in,
                              void* d_out, int out_size, void* d_ws, size_t ws_size,
                              hipStream_t stream) {
    (void)in_sizes; (void)n_in; (void)out_size; (void)ws_size;
    const float* x   = (const float*)d_in[0];
    const int*   ei  = (const int*)d_in[1];
    const float* ea  = (const float*)d_in[2];
    /* d_in[3] = batch (unused, fixed layout) */
    const float* Wl  = (const float*)d_in[4];
    const float* Wr  = (const float*)d_in[5];
    const float* We  = (const float*)d_in[6];
    const float* att = (const float*)d_in[7];
    const float* bg  = (const float*)d_in[8];
    const float* W   = (const float*)d_in[9];
    const float* lb  = (const float*)d_in[10];
    float* out = (float*)d_out;

    char* p = (char*)d_ws;
    float* xl           = (float*)p;          p += 16777216;           // 16384x256 f32
    float* xr           = (float*)p;          p += 16777216;
    unsigned short* hb  = (unsigned short*)p; p += 8388608;            // 16384x256 bf16
    float* parts        = (float*)p;          p += 33554432;           // 8x256x4096 f32
    float* eapart       = (float*)p;          p += 16384;              // 256x16
    float* eeself       = (float*)p;          p += 1024;               // 256

    k_ea_part  <<<256,  256, 0, stream>>>(ea, eapart);
    k_ea_finish<<<1,    256, 0, stream>>>(eapart, We, eeself);
    k_xlr2     <<<dim3(256, 4), 256, 0, stream>>>(x, Wl, Wr, xl, xr);
    k_attn     <<<1024, 256, 0, stream>>>(ei, ea, eeself, att, We, xl, xr, bg, hb);
    k_gemm     <<<dim3(64, 8), 256, 0, stream>>>(hb, W, parts);
    k_reduce   <<<4096, 256, 0, stream>>>(parts, lb, out);
}

// Round 6
// 197.229 us; speedup vs baseline: 1.0657x; 1.0657x over previous
//
#include <hip/hip_runtime.h>
#include <hip/hip_bf16.h>

// Problem constants (fixed by reference)
#define N_NODES   16384
#define DEG       16
#define EDGES     262144          // N_NODES*DEG
#define HC        256             // HEADS*OUT_C
#define KDIM      16384           // 64 nodes * 256 feat
#define NEG_SLOPE 0.2f

typedef __attribute__((ext_vector_type(8))) short short8;   // 8 bf16
typedef __attribute__((ext_vector_type(4))) float floatx4;

static __device__ __forceinline__ unsigned short f2bf(float f) {
    union { __hip_bfloat16 h; unsigned short u; } c;
    c.h = __float2bfloat16(f);          // RNE
    return c.u;
}
static __device__ __forceinline__ unsigned int packbf2(float lo, float hi) {
    union { __hip_bfloat162 h2; unsigned int u; } c;
    c.h2 = __float22bfloat162_rn(make_float2(lo, hi));   // v_cvt_pk_bf16_f32
    return c.u;
}

// DPP row_shr add: v += (lane i-N of 16-lane row, 0 if OOB). After the
// {1,2,4,8} chain, lane l15==15 holds the 16-lane sum (row_shr == shfl_up dir).
template <int CTRL>
static __device__ __forceinline__ float dpp_add(float v) {
    int x = __builtin_amdgcn_update_dpp(0, __float_as_int(v), CTRL, 0xF, 0xF, true);
    return v + __int_as_float(x);
}

// ---- mean(edge_attr) partial sums: 256 blocks x 1024 rows -----------------
__global__ __launch_bounds__(256) void k_ea_part(const float* __restrict__ ea,
                                                 float* __restrict__ part) {
    __shared__ float s[256];
    int b = blockIdx.x, t = threadIdx.x;
    int col = t & 15, r0 = t >> 4;
    const float* base = ea + (size_t)b * 1024 * 16;
    float acc = 0.f;
    for (int r = r0; r < 1024; r += 16) acc += base[r * 16 + col];
    s[t] = acc; __syncthreads();
    for (int off = 128; off >= 16; off >>= 1) {
        if (t < off) s[t] += s[t + off];
        __syncthreads();
    }
    if (t < 16) part[b * 16 + t] = s[t];
}

// ---- finish mean + ee_self = mean_ea @ W_e ---------------------------------
__global__ __launch_bounds__(256) void k_ea_finish(const float* __restrict__ part,
                                                   const float* __restrict__ We,
                                                   float* __restrict__ eeself) {
    __shared__ float mean[16];
    int t = threadIdx.x;
    if (t < 16) {
        float a = 0.f;
        for (int b = 0; b < 256; ++b) a += part[b * 16 + t];
        mean[t] = a * (1.f / (float)EDGES);
    }
    __syncthreads();
    float acc = 0.f;
    #pragma unroll
    for (int d = 0; d < 16; ++d) acc += mean[d] * We[d * 256 + t];
    eeself[t] = acc;
}

// ---- xl|xr via MFMA: (16384 x 128) @ (128 x 512) ---------------------------
__global__ __launch_bounds__(256) void k_xlr2(const float* __restrict__ x,
                                              const float* __restrict__ Wl,
                                              const float* __restrict__ Wr,
                                              float* __restrict__ xl,
                                              float* __restrict__ xr) {
    __shared__ unsigned short As[64][40];   // [row][k] bf16
    __shared__ unsigned int   Bs[128][18];  // [col][kpair]
    unsigned int* As32 = (unsigned int*)&As[0][0];

    int t = threadIdx.x;
    int wave = t >> 6, lane = t & 63;
    int l15 = lane & 15, lk = lane >> 4;
    int wm = wave >> 1, wn = wave & 1;
    int m0 = blockIdx.x * 64;
    int n0 = blockIdx.y * 128;
    const float* Wsel = (n0 < 256) ? Wl : Wr;
    int bc = n0 & 255;

    floatx4 acc[2][4];
    #pragma unroll
    for (int i = 0; i < 2; ++i)
        #pragma unroll
        for (int j = 0; j < 4; ++j)
            acc[i][j] = (floatx4)(0.f);

    int ar = t >> 2, ac = t & 3;
    int bkp = t >> 4, bcc = t & 15;

    for (int k0 = 0; k0 < 128; k0 += 32) {
        __syncthreads();
        {   // stage A: x[m0+r][k0 + ac*8 .. +7] -> bf16
            const float* gp = x + (size_t)(m0 + ar) * 128 + k0 + ac * 8;
            float4 v0 = *(const float4*)gp;
            float4 v1 = *(const float4*)(gp + 4);
            As32[ar * 20 + ac * 4 + 0] = packbf2(v0.x, v0.y);
            As32[ar * 20 + ac * 4 + 1] = packbf2(v0.z, v0.w);
            As32[ar * 20 + ac * 4 + 2] = packbf2(v1.x, v1.y);
            As32[ar * 20 + ac * 4 + 3] = packbf2(v1.z, v1.w);
        }
        {   // stage B
            const float* wp = Wsel + (size_t)(k0 + 2 * bkp) * 256 + bc + bcc * 8;
            float4 r0a = *(const float4*)wp;
            float4 r0b = *(const float4*)(wp + 4);
            float4 r1a = *(const float4*)(wp + 256);
            float4 r1b = *(const float4*)(wp + 260);
            Bs[bcc * 8 + 0][bkp] = packbf2(r0a.x, r1a.x);
            Bs[bcc * 8 + 1][bkp] = packbf2(r0a.y, r1a.y);
            Bs[bcc * 8 + 2][bkp] = packbf2(r0a.z, r1a.z);
            Bs[bcc * 8 + 3][bkp] = packbf2(r0a.w, r1a.w);
            Bs[bcc * 8 + 4][bkp] = packbf2(r0b.x, r1b.x);
            Bs[bcc * 8 + 5][bkp] = packbf2(r0b.y, r1b.y);
            Bs[bcc * 8 + 6][bkp] = packbf2(r0b.z, r1b.z);
            Bs[bcc * 8 + 7][bkp] = packbf2(r0b.w, r1b.w);
        }
        __syncthreads();
        short8 a[2], b[4];
        #pragma unroll
        for (int mi = 0; mi < 2; ++mi)
            a[mi] = *(const short8*)&As[wm * 32 + mi * 16 + l15][lk * 8];
        #pragma unroll
        for (int ni = 0; ni < 4; ++ni) {
            int nr = wn * 64 + ni * 16 + l15;
            union { uint2 u[2]; short8 v; } bb;
            bb.u[0] = *(const uint2*)&Bs[nr][lk * 4];
            bb.u[1] = *(const uint2*)&Bs[nr][lk * 4 + 2];
            b[ni] = bb.v;
        }
        #pragma unroll
        for (int mi = 0; mi < 2; ++mi)
            #pragma unroll
            for (int ni = 0; ni < 4; ++ni)
                acc[mi][ni] = __builtin_amdgcn_mfma_f32_16x16x32_bf16(a[mi], b[ni], acc[mi][ni], 0, 0, 0);
    }

    #pragma unroll
    for (int mi = 0; mi < 2; ++mi) {
        #pragma unroll
        for (int ni = 0; ni < 4; ++ni) {
            int n = n0 + wn * 64 + ni * 16 + l15;
            #pragma unroll
            for (int r = 0; r < 4; ++r) {
                int node = m0 + wm * 32 + mi * 16 + lk * 4 + r;
                if (n0 < 256) xl[(size_t)node * 256 + n]         = acc[mi][ni][r];
                else          xr[(size_t)node * 256 + (n - 256)] = acc[mi][ni][r];
            }
        }
    }
}

// ---- fused GAT attention: MFMA ee + DPP logit reduce + softmax + agg -------
__global__ __launch_bounds__(256) void k_attn(const int* __restrict__ ei,
                                              const float* __restrict__ ea,
                                              const float* __restrict__ eeself,
                                              const float* __restrict__ att,
                                              const float* __restrict__ We,
                                              const float* __restrict__ xl,
                                              const float* __restrict__ xr,
                                              const float* __restrict__ bg,
                                              unsigned short* __restrict__ hb) {
    __shared__ float xlS[64][65];
    __shared__ float xrS[64][65];
    __shared__ float lgS[1088];
    __shared__ int   srcS[1024];

    int t = threadIdx.x;
    int g = blockIdx.x >> 2, h = blockIdx.x & 3;
    int hc0 = h * 64;

    {   // stage xl/xr head slices
        int n = t >> 2, q4 = t & 3;
        const float* xlp = xl + ((size_t)(g * 64 + n)) * 256 + hc0 + q4 * 16;
        const float* xrp = xr + ((size_t)(g * 64 + n)) * 256 + hc0 + q4 * 16;
        #pragma unroll
        for (int i = 0; i < 4; ++i) {
            *(float4*)&xlS[n][q4 * 16 + i * 4] = *(const float4*)(xlp + i * 4);
            *(float4*)&xrS[n][q4 * 16 + i * 4] = *(const float4*)(xrp + i * 4);
        }
    }
    {   // stage local src indices
        int4 v = *(const int4*)(ei + (size_t)g * 1024 + t * 4);
        srcS[t * 4 + 0] = v.x & 63;
        srcS[t * 4 + 1] = v.y & 63;
        srcS[t * 4 + 2] = v.z & 63;
        srcS[t * 4 + 3] = v.w & 63;
    }

    int wave = t >> 6, lane = t & 63;
    int q = lane >> 4, l15 = lane & 15;

    short8 wf[4];
    float  attv[4];
    #pragma unroll
    for (int nt = 0; nt < 4; ++nt) {
        attv[nt] = att[hc0 + nt * 16 + l15];
        if (q < 2) {
            const float* wp = We + (size_t)(q * 8) * 256 + hc0 + nt * 16 + l15;
            float w0 = wp[0*256], w1 = wp[1*256], w2 = wp[2*256], w3 = wp[3*256];
            float w4 = wp[4*256], w5 = wp[5*256], w6 = wp[6*256], w7 = wp[7*256];
            union { unsigned int u[4]; short8 v; } bb;
            bb.u[0] = packbf2(w0, w1);
            bb.u[1] = packbf2(w2, w3);
            bb.u[2] = packbf2(w4, w5);
            bb.u[3] = packbf2(w6, w7);
            wf[nt] = bb.v;
        } else {
            wf[nt] = (short8)0;
        }
    }
    __syncthreads();

    for (int b = wave; b < 16; b += 4) {
        short8 af[4];
        #pragma unroll
        for (int mt = 0; mt < 4; ++mt) {
            if (q < 2) {
                const float* ep = ea + ((size_t)(g * 1024 + b * 64 + mt * 16 + l15)) * 16 + q * 8;
                float4 v0 = *(const float4*)ep;
                float4 v1 = *(const float4*)(ep + 4);
                union { unsigned int u[4]; short8 v; } bb;
                bb.u[0] = packbf2(v0.x, v0.y);
                bb.u[1] = packbf2(v0.z, v0.w);
                bb.u[2] = packbf2(v1.x, v1.y);
                bb.u[3] = packbf2(v1.z, v1.w);
                af[mt] = bb.v;
            } else {
                af[mt] = (short8)0;
            }
        }
        floatx4 acc[4][4];
        #pragma unroll
        for (int mt = 0; mt < 4; ++mt)
            #pragma unroll
            for (int nt = 0; nt < 4; ++nt)
                acc[mt][nt] = __builtin_amdgcn_mfma_f32_16x16x32_bf16(af[mt], wf[nt], (floatx4)(0.f), 0, 0, 0);

        int srcr[4][4];
        #pragma unroll
        for (int mt = 0; mt < 4; ++mt)
            #pragma unroll
            for (int r = 0; r < 4; ++r)
                srcr[mt][r] = srcS[b * 64 + mt * 16 + q * 4 + r];

        #pragma unroll
        for (int mt = 0; mt < 4; ++mt) {
            float lsum[4] = {0.f, 0.f, 0.f, 0.f};
            #pragma unroll
            for (int nt = 0; nt < 4; ++nt) {
                float xrv = xrS[b * 4 + mt][nt * 16 + l15];
                #pragma unroll
                for (int r = 0; r < 4; ++r) {
                    float f = acc[mt][nt][r] + xlS[srcr[mt][r]][nt * 16 + l15] + xrv;
                    f = fmaxf(f, NEG_SLOPE * f);
                    lsum[r] += f * attv[nt];
                }
            }
            #pragma unroll
            for (int r = 0; r < 4; ++r) {
                float v = lsum[r];
                v = dpp_add<0x111>(v);   // row_shr:1
                v = dpp_add<0x112>(v);   // row_shr:2
                v = dpp_add<0x114>(v);   // row_shr:4
                v = dpp_add<0x118>(v);   // row_shr:8 -> lane 15 of the 16-group
                if (l15 == 15) lgS[b * 64 + mt * 16 + q * 4 + r] = v;
            }
        }
    }

    {   // self-loop batch
        int n = wave * 16 + l15;
        float sum = 0.f;
        const float* eep = eeself + hc0 + q * 16;
        const float* ap  = att + hc0 + q * 16;
        #pragma unroll
        for (int i = 0; i < 4; ++i) {
            float4 ev = *(const float4*)(eep + i * 4);
            float4 av = *(const float4*)(ap + i * 4);
            #pragma unroll
            for (int j = 0; j < 4; ++j) {
                int c = q * 16 + i * 4 + j;
                float e = (j == 0) ? ev.x : (j == 1) ? ev.y : (j == 2) ? ev.z : ev.w;
                float a = (j == 0) ? av.x : (j == 1) ? av.y : (j == 2) ? av.z : av.w;
                float f = xlS[n][c] + xrS[n][c] + e;
                f = fmaxf(f, NEG_SLOPE * f);
                sum += f * a;
            }
        }
        sum += __shfl_xor(sum, 16);
        sum += __shfl_xor(sum, 32);
        if (q == 0) lgS[1024 + n] = sum;
    }
    __syncthreads();

    if (t < 64) {
        float lg[17];
        #pragma unroll
        for (int j = 0; j < 16; ++j) lg[j] = lgS[t * 16 + j];
        lg[16] = lgS[1024 + t];
        float m = lg[0];
        #pragma unroll
        for (int j = 1; j < 17; ++j) m = fmaxf(m, lg[j]);
        float ex[17], ssum = 0.f;
        #pragma unroll
        for (int j = 0; j < 17; ++j) { ex[j] = __expf(lg[j] - m); ssum += ex[j]; }
        float inv = 1.f / (17.f * ssum);
        #pragma unroll
        for (int j = 0; j < 16; ++j) lgS[t * 16 + j] = ex[j] * inv;
        lgS[1024 + t] = ex[16] * inv;
    }
    __syncthreads();

    {
        int c = lane;
        float bgv = bg[hc0 + c];
        for (int n = wave * 16; n < wave * 16 + 16; ++n) {
            float a0 = lgS[1024 + n] * xlS[n][c];
            float a1 = 0.f;
            #pragma unroll
            for (int j = 0; j < 16; j += 2) {
                a0 += lgS[n * 16 + j]     * xlS[srcS[n * 16 + j]][c];
                a1 += lgS[n * 16 + j + 1] * xlS[srcS[n * 16 + j + 1]][c];
            }
            float val = a0 + a1 + bgv;
            hb[((size_t)(g * 64 + n)) * 256 + hc0 + c] = f2bf(val);
        }
    }
}

// ---- big GEMM v7: 1-iter-deep prefetch, counted vmcnt, unroll-2 ------------
// (256 x 16384) bf16 @ W[16384 x 4096] -> partials[s][256][4096]
// Per iter j: issue A(j+1), B(j+2); vmcnt(8)->A(j); COMPUTE; vmcnt(6)->B(j+1);
// WRITE_B; barrier.  Both A and B get >= 1 full iteration of latency hiding.
__global__ __launch_bounds__(256) void k_gemm(const unsigned short* __restrict__ hb,
                                              const float* __restrict__ W,
                                              float* __restrict__ parts) {
    __shared__ unsigned short As[2][256 * 32];
    __shared__ unsigned int   Bs[2][64][18];

    int t = threadIdx.x;
    int wave = t >> 6, lane = t & 63;
    int l15 = lane & 15, lk = lane >> 4;
    int n0 = blockIdx.x * 64;
    int s  = blockIdx.y;
    int kbase = s * 2048;

    floatx4 acc[4][4];
    #pragma unroll
    for (int i = 0; i < 4; ++i)
        #pragma unroll
        for (int j = 0; j < 4; ++j)
            acc[i][j] = (floatx4)(0.f);

    // A-load: swizzled global source (rule 21), linear LDS dest.
    // stored chunk pos of global chunk g at row R: (g + (R>>1)) & 3
    int gc = ((lane & 3) - ((lane >> 3) & 3)) & 3;
    const unsigned short* a_src =
        hb + (size_t)(wave * 64 + (lane >> 2)) * KDIM + kbase + gc * 8;
    int ap_off[4];
    #pragma unroll
    for (int mi = 0; mi < 4; ++mi)
        ap_off[mi] = (wave * 64 + mi * 16 + l15) * 32 + (((lk + (l15 >> 1)) & 3) * 8);

    int bkp = t >> 4;     // 0..15 row-pair
    int bc8 = t & 15;     // col chunk (4 cols)
    const float* b_src = W + (size_t)(kbase + 2 * bkp) * 4096 + n0 + bc8 * 4;

    #define ISSUE_A(step, buf)                                                   \
        {                                                                        \
            const unsigned short* gp_ = a_src + (size_t)(step) * 32;             \
            _Pragma("unroll")                                                    \
            for (int i_ = 0; i_ < 4; ++i_) {                                     \
                __builtin_amdgcn_global_load_lds(                                \
                    (const __attribute__((address_space(1))) unsigned int*)      \
                        (gp_ + (size_t)i_ * 16 * KDIM),                          \
                    (__attribute__((address_space(3))) unsigned int*)            \
                        &As[buf][(wave * 64 + i_ * 16) * 32],                    \
                    16, 0, 0);                                                   \
            }                                                                    \
        }
    #define LOAD_B(step, r0, r1)                                                 \
        {                                                                        \
            const float* wp_ = b_src + (size_t)(step) * 32 * 4096;               \
            r0 = *(const float4*)wp_;                                            \
            r1 = *(const float4*)(wp_ + 4096);                                   \
        }
    #define WRITE_B(buf, r0, r1)                                                 \
        {                                                                        \
            Bs[buf][bc8 * 4 + 0][bkp] = packbf2(r0.x, r1.x);                     \
            Bs[buf][bc8 * 4 + 1][bkp] = packbf2(r0.y, r1.y);                     \
            Bs[buf][bc8 * 4 + 2][bkp] = packbf2(r0.z, r1.z);                     \
            Bs[buf][bc8 * 4 + 3][bkp] = packbf2(r0.w, r1.w);                     \
        }
    #define COMPUTE(abuf, bbuf)                                                  \
        {                                                                        \
            short8 a_[4], b_[4];                                                 \
            _Pragma("unroll")                                                    \
            for (int mi = 0; mi < 4; ++mi)                                       \
                a_[mi] = *(const short8*)&As[abuf][ap_off[mi]];                  \
            _Pragma("unroll")                                                    \
            for (int ni = 0; ni < 4; ++ni) {                                     \
                int nr_ = ni * 16 + l15;                                         \
                union { uint2 u[2]; short8 v; } bb_;                             \
                bb_.u[0] = *(const uint2*)&Bs[bbuf][nr_][lk * 4];                \
                bb_.u[1] = *(const uint2*)&Bs[bbuf][nr_][lk * 4 + 2];            \
                b_[ni] = bb_.v;                                                  \
            }                                                                    \
            __builtin_amdgcn_s_setprio(1);                                       \
            _Pragma("unroll")                                                    \
            for (int mi = 0; mi < 4; ++mi)                                       \
                _Pragma("unroll")                                                \
                for (int ni = 0; ni < 4; ++ni)                                   \
                    acc[mi][ni] = __builtin_amdgcn_mfma_f32_16x16x32_bf16(       \
                        a_[mi], b_[ni], acc[mi][ni], 0, 0, 0);                   \
            __builtin_amdgcn_s_setprio(0);                                       \
        }
    #define VMCNT(n) __builtin_amdgcn_sched_barrier(0);                          \
                     asm volatile("s_waitcnt vmcnt(" #n ")" ::: "memory");       \
                     __builtin_amdgcn_sched_barrier(0)
    #define LGKM0    asm volatile("s_waitcnt lgkmcnt(0)" ::: "memory");          \
                     __builtin_amdgcn_sched_barrier(0)

    float4 e0, e1, o0, o1;   // B reg sets: even iters issue into e, odd into o

    // ---- prologue: A(0), B(0)->e, B(1)->o; write Bs[0] ----
    ISSUE_A(0, 0);
    LOAD_B(0, e0, e1);
    LOAD_B(1, o0, o1);
    VMCNT(2);                 // A(0), B(0) done; B(1) in flight
    WRITE_B(0, e0, e1);
    LGKM0;
    __builtin_amdgcn_s_barrier();

    // ---- steady: iters 0..61, unrolled by 2 ----
    for (int j = 0; j < 62; j += 2) {
        // even iter j: compute As[0],Bs[0]; issue A(j+1)->As[1], B(j+2)->e
        ISSUE_A(j + 1, 1);
        LOAD_B(j + 2, e0, e1);
        VMCNT(8);             // A(j) complete
        COMPUTE(0, 0);
        VMCNT(6);             // B(j+1) complete (issued last iter)
        WRITE_B(1, o0, o1);
        LGKM0;
        __builtin_amdgcn_s_barrier();
        // odd iter j+1: compute As[1],Bs[1]; issue A(j+2)->As[0], B(j+3)->o
        ISSUE_A(j + 2, 0);
        LOAD_B(j + 3, o0, o1);
        VMCNT(8);             // A(j+1) complete
        COMPUTE(1, 1);
        VMCNT(6);             // B(j+2) complete
        WRITE_B(0, e0, e1);
        LGKM0;
        __builtin_amdgcn_s_barrier();
    }
    // ---- peel iter 62 (even): entry [A(62):4, B(63):2] ----
    {
        ISSUE_A(63, 1);
        VMCNT(6);             // A(62) complete
        COMPUTE(0, 0);
        VMCNT(4);             // B(63) complete (in o-set from iter 61)
        WRITE_B(1, o0, o1);
        LGKM0;
        __builtin_amdgcn_s_barrier();
    }
    // ---- peel iter 63 (odd) ----
    VMCNT(0);                 // A(63) complete
    COMPUTE(1, 1);

    #undef ISSUE_A
    #undef LOAD_B
    #undef WRITE_B
    #undef COMPUTE
    #undef VMCNT
    #undef LGKM0

    float* dst = parts + (size_t)s * (256 * 4096);
    #pragma unroll
    for (int mi = 0; mi < 4; ++mi) {
        #pragma unroll
        for (int ni = 0; ni < 4; ++ni) {
            int col = n0 + ni * 16 + l15;
            #pragma unroll
            for (int r = 0; r < 4; ++r) {
                int row = wave * 64 + mi * 16 + lk * 4 + r;
                dst[(size_t)row * 4096 + col] = acc[mi][ni][r];
            }
        }
    }
}

// ---- reduce partials + bias -> d_out ---------------------------------------
__global__ __launch_bounds__(256) void k_reduce(const float* __restrict__ parts,
                                                const float* __restrict__ linb,
                                                float* __restrict__ out) {
    int idx = blockIdx.x * 256 + threadIdx.x;
    float v = linb[idx & 4095];
    #pragma unroll
    for (int s = 0; s < 8; ++s) v += parts[(size_t)s * (256 * 4096) + idx];
    out[idx] = v;
}

extern "C" void kernel_launch(void* const* d_in, const int* in_sizes, int n_in,
                              void* d_out, int out_size, void* d_ws, size_t ws_size,
                              hipStream_t stream) {
    (void)in_sizes; (void)n_in; (void)out_size; (void)ws_size;
    const float* x   = (const float*)d_in[0];
    const int*   ei  = (const int*)d_in[1];
    const float* ea  = (const float*)d_in[2];
    /* d_in[3] = batch (unused, fixed layout) */
    const float* Wl  = (const float*)d_in[4];
    const float* Wr  = (const float*)d_in[5];
    const float* We  = (const float*)d_in[6];
    const float* att = (const float*)d_in[7];
    const float* bg  = (const float*)d_in[8];
    const float* W   = (const float*)d_in[9];
    const float* lb  = (const float*)d_in[10];
    float* out = (float*)d_out;

    char* p = (char*)d_ws;
    float* xl           = (float*)p;          p += 16777216;           // 16384x256 f32
    float* xr           = (float*)p;          p += 16777216;
    unsigned short* hb  = (unsigned short*)p; p += 8388608;            // 16384x256 bf16
    float* parts        = (float*)p;          p += 33554432;           // 8x256x4096 f32
    float* eapart       = (float*)p;          p += 16384;              // 256x16
    float* eeself       = (float*)p;          p += 1024;               // 256

    k_ea_part  <<<256,  256, 0, stream>>>(ea, eapart);
    k_ea_finish<<<1,    256, 0, stream>>>(eapart, We, eeself);
    k_xlr2     <<<dim3(256, 4), 256, 0, stream>>>(x, Wl, Wr, xl, xr);
    k_attn     <<<1024, 256, 0, stream>>>(ei, ea, eeself, att, We, xl, xr, bg, hb);
    k_gemm     <<<dim3(64, 8), 256, 0, stream>>>(hb, W, parts);
    k_reduce   <<<4096, 256, 0, stream>>>(parts, lb, out);
}

// Round 7
// 193.671 us; speedup vs baseline: 1.0852x; 1.0184x over previous
//
#include <hip/hip_runtime.h>
#include <hip/hip_bf16.h>

// Problem constants (fixed by reference)
#define N_NODES   16384
#define DEG       16
#define EDGES     262144          // N_NODES*DEG
#define HC        256             // HEADS*OUT_C
#define KDIM      16384           // 64 nodes * 256 feat
#define NEG_SLOPE 0.2f

typedef __attribute__((ext_vector_type(8))) short short8;   // 8 bf16
typedef __attribute__((ext_vector_type(4))) float floatx4;

static __device__ __forceinline__ unsigned short f2bf(float f) {
    union { __hip_bfloat16 h; unsigned short u; } c;
    c.h = __float2bfloat16(f);          // RNE
    return c.u;
}
static __device__ __forceinline__ unsigned int packbf2(float lo, float hi) {
    union { __hip_bfloat162 h2; unsigned int u; } c;
    c.h2 = __float22bfloat162_rn(make_float2(lo, hi));   // v_cvt_pk_bf16_f32
    return c.u;
}

// DPP row_shr add chain {1,2,4,8}: lane l15==15 holds the 16-lane sum.
template <int CTRL>
static __device__ __forceinline__ float dpp_add(float v) {
    int x = __builtin_amdgcn_update_dpp(0, __float_as_int(v), CTRL, 0xF, 0xF, true);
    return v + __int_as_float(x);
}

// ---- mean(edge_attr) partial sums: 256 blocks x 1024 rows -----------------
__global__ __launch_bounds__(256) void k_ea_part(const float* __restrict__ ea,
                                                 float* __restrict__ part) {
    __shared__ float s[256];
    int b = blockIdx.x, t = threadIdx.x;
    int col = t & 15, r0 = t >> 4;
    const float* base = ea + (size_t)b * 1024 * 16;
    float acc = 0.f;
    for (int r = r0; r < 1024; r += 16) acc += base[r * 16 + col];
    s[t] = acc; __syncthreads();
    for (int off = 128; off >= 16; off >>= 1) {
        if (t < off) s[t] += s[t + off];
        __syncthreads();
    }
    if (t < 16) part[b * 16 + t] = s[t];
}

// ---- finish mean + ee_self = mean_ea @ W_e ---------------------------------
__global__ __launch_bounds__(256) void k_ea_finish(const float* __restrict__ part,
                                                   const float* __restrict__ We,
                                                   float* __restrict__ eeself) {
    __shared__ float mean[16];
    int t = threadIdx.x;
    if (t < 16) {
        float a = 0.f;
        for (int b = 0; b < 256; ++b) a += part[b * 16 + t];
        mean[t] = a * (1.f / (float)EDGES);
    }
    __syncthreads();
    float acc = 0.f;
    #pragma unroll
    for (int d = 0; d < 16; ++d) acc += mean[d] * We[d * 256 + t];
    eeself[t] = acc;
}

// ---- xl|xr via MFMA: (16384 x 128) @ (128 x 512) ---------------------------
__global__ __launch_bounds__(256) void k_xlr2(const float* __restrict__ x,
                                              const float* __restrict__ Wl,
                                              const float* __restrict__ Wr,
                                              float* __restrict__ xl,
                                              float* __restrict__ xr) {
    __shared__ unsigned short As[64][40];   // [row][k] bf16
    __shared__ unsigned int   Bs[128][18];  // [col][kpair]
    unsigned int* As32 = (unsigned int*)&As[0][0];

    int t = threadIdx.x;
    int wave = t >> 6, lane = t & 63;
    int l15 = lane & 15, lk = lane >> 4;
    int wm = wave >> 1, wn = wave & 1;
    int m0 = blockIdx.x * 64;
    int n0 = blockIdx.y * 128;
    const float* Wsel = (n0 < 256) ? Wl : Wr;
    int bc = n0 & 255;

    floatx4 acc[2][4];
    #pragma unroll
    for (int i = 0; i < 2; ++i)
        #pragma unroll
        for (int j = 0; j < 4; ++j)
            acc[i][j] = (floatx4)(0.f);

    int ar = t >> 2, ac = t & 3;
    int bkp = t >> 4, bcc = t & 15;

    for (int k0 = 0; k0 < 128; k0 += 32) {
        __syncthreads();
        {   // stage A: x[m0+r][k0 + ac*8 .. +7] -> bf16
            const float* gp = x + (size_t)(m0 + ar) * 128 + k0 + ac * 8;
            float4 v0 = *(const float4*)gp;
            float4 v1 = *(const float4*)(gp + 4);
            As32[ar * 20 + ac * 4 + 0] = packbf2(v0.x, v0.y);
            As32[ar * 20 + ac * 4 + 1] = packbf2(v0.z, v0.w);
            As32[ar * 20 + ac * 4 + 2] = packbf2(v1.x, v1.y);
            As32[ar * 20 + ac * 4 + 3] = packbf2(v1.z, v1.w);
        }
        {   // stage B
            const float* wp = Wsel + (size_t)(k0 + 2 * bkp) * 256 + bc + bcc * 8;
            float4 r0a = *(const float4*)wp;
            float4 r0b = *(const float4*)(wp + 4);
            float4 r1a = *(const float4*)(wp + 256);
            float4 r1b = *(const float4*)(wp + 260);
            Bs[bcc * 8 + 0][bkp] = packbf2(r0a.x, r1a.x);
            Bs[bcc * 8 + 1][bkp] = packbf2(r0a.y, r1a.y);
            Bs[bcc * 8 + 2][bkp] = packbf2(r0a.z, r1a.z);
            Bs[bcc * 8 + 3][bkp] = packbf2(r0a.w, r1a.w);
            Bs[bcc * 8 + 4][bkp] = packbf2(r0b.x, r1b.x);
            Bs[bcc * 8 + 5][bkp] = packbf2(r0b.y, r1b.y);
            Bs[bcc * 8 + 6][bkp] = packbf2(r0b.z, r1b.z);
            Bs[bcc * 8 + 7][bkp] = packbf2(r0b.w, r1b.w);
        }
        __syncthreads();
        short8 a[2], b[4];
        #pragma unroll
        for (int mi = 0; mi < 2; ++mi)
            a[mi] = *(const short8*)&As[wm * 32 + mi * 16 + l15][lk * 8];
        #pragma unroll
        for (int ni = 0; ni < 4; ++ni) {
            int nr = wn * 64 + ni * 16 + l15;
            union { uint2 u[2]; short8 v; } bb;
            bb.u[0] = *(const uint2*)&Bs[nr][lk * 4];
            bb.u[1] = *(const uint2*)&Bs[nr][lk * 4 + 2];
            b[ni] = bb.v;
        }
        #pragma unroll
        for (int mi = 0; mi < 2; ++mi)
            #pragma unroll
            for (int ni = 0; ni < 4; ++ni)
                acc[mi][ni] = __builtin_amdgcn_mfma_f32_16x16x32_bf16(a[mi], b[ni], acc[mi][ni], 0, 0, 0);
    }

    #pragma unroll
    for (int mi = 0; mi < 2; ++mi) {
        #pragma unroll
        for (int ni = 0; ni < 4; ++ni) {
            int n = n0 + wn * 64 + ni * 16 + l15;
            #pragma unroll
            for (int r = 0; r < 4; ++r) {
                int node = m0 + wm * 32 + mi * 16 + lk * 4 + r;
                if (n0 < 256) xl[(size_t)node * 256 + n]         = acc[mi][ni][r];
                else          xr[(size_t)node * 256 + (n - 256)] = acc[mi][ni][r];
            }
        }
    }
}

// ---- fused GAT attention v5: permuted LDS layout, vectorized DS traffic ----
// Column permutation: logical col c stored at p(c) = (c&15)*4 + (c>>4).
// Consequence: cols {nt*16 + l15, nt=0..3} are CONTIGUOUS at [l15*4 .. +3]
// -> one ds_read_b128 per (item) instead of 4 stride-16 b32 reads.
__global__ __launch_bounds__(256) void k_attn(const int* __restrict__ ei,
                                              const float* __restrict__ ea,
                                              const float* __restrict__ eeself,
                                              const float* __restrict__ att,
                                              const float* __restrict__ We,
                                              const float* __restrict__ xl,
                                              const float* __restrict__ xr,
                                              const float* __restrict__ bg,
                                              unsigned short* __restrict__ hb) {
    __shared__ float xlS[64][68];    // permuted cols, pitch 68 (272B, 16B-mult)
    __shared__ float xrS[64][68];
    __shared__ float lgS[1088];
    __shared__ int   srcS[1024];

    int t = threadIdx.x;
    int g = blockIdx.x >> 2, h = blockIdx.x & 3;
    int hc0 = h * 64;

    {   // stage xl/xr head slices into PERMUTED layout
        int n = t >> 2, q4 = t & 3;
        const float* xlp = xl + ((size_t)(g * 64 + n)) * 256 + hc0 + q4 * 16;
        const float* xrp = xr + ((size_t)(g * 64 + n)) * 256 + hc0 + q4 * 16;
        #pragma unroll
        for (int i = 0; i < 4; ++i) {
            // logical c = q4*16 + i*4 + j  ->  p = (i*4+j)*4 + q4
            float4 vl = *(const float4*)(xlp + i * 4);
            float4 vr = *(const float4*)(xrp + i * 4);
            xlS[n][(i * 4 + 0) * 4 + q4] = vl.x;
            xlS[n][(i * 4 + 1) * 4 + q4] = vl.y;
            xlS[n][(i * 4 + 2) * 4 + q4] = vl.z;
            xlS[n][(i * 4 + 3) * 4 + q4] = vl.w;
            xrS[n][(i * 4 + 0) * 4 + q4] = vr.x;
            xrS[n][(i * 4 + 1) * 4 + q4] = vr.y;
            xrS[n][(i * 4 + 2) * 4 + q4] = vr.z;
            xrS[n][(i * 4 + 3) * 4 + q4] = vr.w;
        }
    }
    {   // stage local src indices
        int4 v = *(const int4*)(ei + (size_t)g * 1024 + t * 4);
        srcS[t * 4 + 0] = v.x & 63;
        srcS[t * 4 + 1] = v.y & 63;
        srcS[t * 4 + 2] = v.z & 63;
        srcS[t * 4 + 3] = v.w & 63;
    }

    int wave = t >> 6, lane = t & 63;
    int q = lane >> 4, l15 = lane & 15;

    short8 wf[4];
    float  attv[4];
    #pragma unroll
    for (int nt = 0; nt < 4; ++nt) {
        attv[nt] = att[hc0 + nt * 16 + l15];
        if (q < 2) {
            const float* wp = We + (size_t)(q * 8) * 256 + hc0 + nt * 16 + l15;
            float w0 = wp[0*256], w1 = wp[1*256], w2 = wp[2*256], w3 = wp[3*256];
            float w4 = wp[4*256], w5 = wp[5*256], w6 = wp[6*256], w7 = wp[7*256];
            union { unsigned int u[4]; short8 v; } bb;
            bb.u[0] = packbf2(w0, w1);
            bb.u[1] = packbf2(w2, w3);
            bb.u[2] = packbf2(w4, w5);
            bb.u[3] = packbf2(w6, w7);
            wf[nt] = bb.v;
        } else {
            wf[nt] = (short8)0;
        }
    }
    __syncthreads();

    for (int b = wave; b < 16; b += 4) {
        short8 af[4];
        #pragma unroll
        for (int mt = 0; mt < 4; ++mt) {
            if (q < 2) {
                const float* ep = ea + ((size_t)(g * 1024 + b * 64 + mt * 16 + l15)) * 16 + q * 8;
                float4 v0 = *(const float4*)ep;
                float4 v1 = *(const float4*)(ep + 4);
                union { unsigned int u[4]; short8 v; } bb;
                bb.u[0] = packbf2(v0.x, v0.y);
                bb.u[1] = packbf2(v0.z, v0.w);
                bb.u[2] = packbf2(v1.x, v1.y);
                bb.u[3] = packbf2(v1.z, v1.w);
                af[mt] = bb.v;
            } else {
                af[mt] = (short8)0;
            }
        }
        floatx4 acc[4][4];
        #pragma unroll
        for (int mt = 0; mt < 4; ++mt)
            #pragma unroll
            for (int nt = 0; nt < 4; ++nt)
                acc[mt][nt] = __builtin_amdgcn_mfma_f32_16x16x32_bf16(af[mt], wf[nt], (floatx4)(0.f), 0, 0, 0);

        #pragma unroll
        for (int mt = 0; mt < 4; ++mt) {
            // xr for dst (uniform per mt): all 4 nt components in one b128
            float4 xrv = *(const float4*)&xrS[b * 4 + mt][l15 * 4];
            int4  s4  = *(const int4*)&srcS[b * 64 + mt * 16 + q * 4];
            int sr[4] = {s4.x, s4.y, s4.z, s4.w};
            float lsum[4];
            #pragma unroll
            for (int r = 0; r < 4; ++r) {
                float4 xlv = *(const float4*)&xlS[sr[r]][l15 * 4];
                float f, acc_sum = 0.f;
                f = acc[mt][0][r] + xlv.x + xrv.x; f = fmaxf(f, NEG_SLOPE * f); acc_sum += f * attv[0];
                f = acc[mt][1][r] + xlv.y + xrv.y; f = fmaxf(f, NEG_SLOPE * f); acc_sum += f * attv[1];
                f = acc[mt][2][r] + xlv.z + xrv.z; f = fmaxf(f, NEG_SLOPE * f); acc_sum += f * attv[2];
                f = acc[mt][3][r] + xlv.w + xrv.w; f = fmaxf(f, NEG_SLOPE * f); acc_sum += f * attv[3];
                lsum[r] = acc_sum;
            }
            #pragma unroll
            for (int r = 0; r < 4; ++r) {
                float v = lsum[r];
                v = dpp_add<0x111>(v);
                v = dpp_add<0x112>(v);
                v = dpp_add<0x114>(v);
                v = dpp_add<0x118>(v);
                if (l15 == 15) lgS[b * 64 + mt * 16 + q * 4 + r] = v;
            }
        }
    }

    {   // self-loop batch (permuted indexing: c = q*16+i*4+j -> p = (i*4+j)*4+q)
        int n = wave * 16 + l15;
        float sum = 0.f;
        const float* eep = eeself + hc0 + q * 16;
        const float* ap  = att + hc0 + q * 16;
        #pragma unroll
        for (int i = 0; i < 4; ++i) {
            float4 ev = *(const float4*)(eep + i * 4);
            float4 av = *(const float4*)(ap + i * 4);
            #pragma unroll
            for (int j = 0; j < 4; ++j) {
                int p = (i * 4 + j) * 4 + q;
                float e = (j == 0) ? ev.x : (j == 1) ? ev.y : (j == 2) ? ev.z : ev.w;
                float a = (j == 0) ? av.x : (j == 1) ? av.y : (j == 2) ? av.z : av.w;
                float f = xlS[n][p] + xrS[n][p] + e;
                f = fmaxf(f, NEG_SLOPE * f);
                sum += f * a;
            }
        }
        sum += __shfl_xor(sum, 16);
        sum += __shfl_xor(sum, 32);
        if (q == 0) lgS[1024 + n] = sum;
    }
    __syncthreads();

    if (t < 64) {
        float lg[17];
        #pragma unroll
        for (int j = 0; j < 16; ++j) lg[j] = lgS[t * 16 + j];
        lg[16] = lgS[1024 + t];
        float m = lg[0];
        #pragma unroll
        for (int j = 1; j < 17; ++j) m = fmaxf(m, lg[j]);
        float ex[17], ssum = 0.f;
        #pragma unroll
        for (int j = 0; j < 17; ++j) { ex[j] = __expf(lg[j] - m); ssum += ex[j]; }
        float inv = 1.f / (17.f * ssum);
        #pragma unroll
        for (int j = 0; j < 16; ++j) lgS[t * 16 + j] = ex[j] * inv;
        lgS[1024 + t] = ex[16] * inv;
    }
    __syncthreads();

    {   // aggregation: lane = logical col c; permuted read position pc
        int c = lane;
        int pc = (c & 15) * 4 + (c >> 4);
        float bgv = bg[hc0 + c];
        for (int n = wave * 16; n < wave * 16 + 16; ++n) {
            float4 al0 = *(const float4*)&lgS[n * 16];
            float4 al1 = *(const float4*)&lgS[n * 16 + 4];
            float4 al2 = *(const float4*)&lgS[n * 16 + 8];
            float4 al3 = *(const float4*)&lgS[n * 16 + 12];
            int4  s0  = *(const int4*)&srcS[n * 16];
            int4  s1  = *(const int4*)&srcS[n * 16 + 4];
            int4  s2  = *(const int4*)&srcS[n * 16 + 8];
            int4  s3  = *(const int4*)&srcS[n * 16 + 12];
            // keep exact a0(even j)/a1(odd j) accumulation order of prior rounds
            float a0 = lgS[1024 + n] * xlS[n][pc];
            float a1 = 0.f;
            a0 += al0.x * xlS[s0.x][pc];  a1 += al0.y * xlS[s0.y][pc];
            a0 += al0.z * xlS[s0.z][pc];  a1 += al0.w * xlS[s0.w][pc];
            a0 += al1.x * xlS[s1.x][pc];  a1 += al1.y * xlS[s1.y][pc];
            a0 += al1.z * xlS[s1.z][pc];  a1 += al1.w * xlS[s1.w][pc];
            a0 += al2.x * xlS[s2.x][pc];  a1 += al2.y * xlS[s2.y][pc];
            a0 += al2.z * xlS[s2.z][pc];  a1 += al2.w * xlS[s2.w][pc];
            a0 += al3.x * xlS[s3.x][pc];  a1 += al3.y * xlS[s3.y][pc];
            a0 += al3.z * xlS[s3.z][pc];  a1 += al3.w * xlS[s3.w][pc];
            float val = a0 + a1 + bgv;
            hb[((size_t)(g * 64 + n)) * 256 + hc0 + c] = f2bf(val);
        }
    }
}

// ---- big GEMM v7: 1-iter-deep prefetch, counted vmcnt, unroll-2 ------------
__global__ __launch_bounds__(256) void k_gemm(const unsigned short* __restrict__ hb,
                                              const float* __restrict__ W,
                                              float* __restrict__ parts) {
    __shared__ unsigned short As[2][256 * 32];
    __shared__ unsigned int   Bs[2][64][18];

    int t = threadIdx.x;
    int wave = t >> 6, lane = t & 63;
    int l15 = lane & 15, lk = lane >> 4;
    int n0 = blockIdx.x * 64;
    int s  = blockIdx.y;
    int kbase = s * 2048;

    floatx4 acc[4][4];
    #pragma unroll
    for (int i = 0; i < 4; ++i)
        #pragma unroll
        for (int j = 0; j < 4; ++j)
            acc[i][j] = (floatx4)(0.f);

    int gc = ((lane & 3) - ((lane >> 3) & 3)) & 3;
    const unsigned short* a_src =
        hb + (size_t)(wave * 64 + (lane >> 2)) * KDIM + kbase + gc * 8;
    int ap_off[4];
    #pragma unroll
    for (int mi = 0; mi < 4; ++mi)
        ap_off[mi] = (wave * 64 + mi * 16 + l15) * 32 + (((lk + (l15 >> 1)) & 3) * 8);

    int bkp = t >> 4;
    int bc8 = t & 15;
    const float* b_src = W + (size_t)(kbase + 2 * bkp) * 4096 + n0 + bc8 * 4;

    #define ISSUE_A(step, buf)                                                   \
        {                                                                        \
            const unsigned short* gp_ = a_src + (size_t)(step) * 32;             \
            _Pragma("unroll")                                                    \
            for (int i_ = 0; i_ < 4; ++i_) {                                     \
                __builtin_amdgcn_global_load_lds(                                \
                    (const __attribute__((address_space(1))) unsigned int*)      \
                        (gp_ + (size_t)i_ * 16 * KDIM),                          \
                    (__attribute__((address_space(3))) unsigned int*)            \
                        &As[buf][(wave * 64 + i_ * 16) * 32],                    \
                    16, 0, 0);                                                   \
            }                                                                    \
        }
    #define LOAD_B(step, r0, r1)                                                 \
        {                                                                        \
            const float* wp_ = b_src + (size_t)(step) * 32 * 4096;               \
            r0 = *(const float4*)wp_;                                            \
            r1 = *(const float4*)(wp_ + 4096);                                   \
        }
    #define WRITE_B(buf, r0, r1)                                                 \
        {                                                                        \
            Bs[buf][bc8 * 4 + 0][bkp] = packbf2(r0.x, r1.x);                     \
            Bs[buf][bc8 * 4 + 1][bkp] = packbf2(r0.y, r1.y);                     \
            Bs[buf][bc8 * 4 + 2][bkp] = packbf2(r0.z, r1.z);                     \
            Bs[buf][bc8 * 4 + 3][bkp] = packbf2(r0.w, r1.w);                     \
        }
    #define COMPUTE(abuf, bbuf)                                                  \
        {                                                                        \
            short8 a_[4], b_[4];                                                 \
            _Pragma("unroll")                                                    \
            for (int mi = 0; mi < 4; ++mi)                                       \
                a_[mi] = *(const short8*)&As[abuf][ap_off[mi]];                  \
            _Pragma("unroll")                                                    \
            for (int ni = 0; ni < 4; ++ni) {                                     \
                int nr_ = ni * 16 + l15;                                         \
                union { uint2 u[2]; short8 v; } bb_;                             \
                bb_.u[0] = *(const uint2*)&Bs[bbuf][nr_][lk * 4];                \
                bb_.u[1] = *(const uint2*)&Bs[bbuf][nr_][lk * 4 + 2];            \
                b_[ni] = bb_.v;                                                  \
            }                                                                    \
            __builtin_amdgcn_s_setprio(1);                                       \
            _Pragma("unroll")                                                    \
            for (int mi = 0; mi < 4; ++mi)                                       \
                _Pragma("unroll")                                                \
                for (int ni = 0; ni < 4; ++ni)                                   \
                    acc[mi][ni] = __builtin_amdgcn_mfma_f32_16x16x32_bf16(       \
                        a_[mi], b_[ni], acc[mi][ni], 0, 0, 0);                   \
            __builtin_amdgcn_s_setprio(0);                                       \
        }
    #define VMCNT(n) __builtin_amdgcn_sched_barrier(0);                          \
                     asm volatile("s_waitcnt vmcnt(" #n ")" ::: "memory");       \
                     __builtin_amdgcn_sched_barrier(0)
    #define LGKM0    asm volatile("s_waitcnt lgkmcnt(0)" ::: "memory");          \
                     __builtin_amdgcn_sched_barrier(0)

    float4 e0, e1, o0, o1;

    ISSUE_A(0, 0);
    LOAD_B(0, e0, e1);
    LOAD_B(1, o0, o1);
    VMCNT(2);
    WRITE_B(0, e0, e1);
    LGKM0;
    __builtin_amdgcn_s_barrier();

    for (int j = 0; j < 62; j += 2) {
        ISSUE_A(j + 1, 1);
        LOAD_B(j + 2, e0, e1);
        VMCNT(8);
        COMPUTE(0, 0);
        VMCNT(6);
        WRITE_B(1, o0, o1);
        LGKM0;
        __builtin_amdgcn_s_barrier();
        ISSUE_A(j + 2, 0);
        LOAD_B(j + 3, o0, o1);
        VMCNT(8);
        COMPUTE(1, 1);
        VMCNT(6);
        WRITE_B(0, e0, e1);
        LGKM0;
        __builtin_amdgcn_s_barrier();
    }
    {
        ISSUE_A(63, 1);
        VMCNT(6);
        COMPUTE(0, 0);
        VMCNT(4);
        WRITE_B(1, o0, o1);
        LGKM0;
        __builtin_amdgcn_s_barrier();
    }
    VMCNT(0);
    COMPUTE(1, 1);

    #undef ISSUE_A
    #undef LOAD_B
    #undef WRITE_B
    #undef COMPUTE
    #undef VMCNT
    #undef LGKM0

    float* dst = parts + (size_t)s * (256 * 4096);
    #pragma unroll
    for (int mi = 0; mi < 4; ++mi) {
        #pragma unroll
        for (int ni = 0; ni < 4; ++ni) {
            int col = n0 + ni * 16 + l15;
            #pragma unroll
            for (int r = 0; r < 4; ++r) {
                int row = wave * 64 + mi * 16 + lk * 4 + r;
                dst[(size_t)row * 4096 + col] = acc[mi][ni][r];
            }
        }
    }
}

// ---- reduce partials + bias -> d_out ---------------------------------------
__global__ __launch_bounds__(256) void k_reduce(const float* __restrict__ parts,
                                                const float* __restrict__ linb,
                                                float* __restrict__ out) {
    int idx = blockIdx.x * 256 + threadIdx.x;
    float v = linb[idx & 4095];
    #pragma unroll
    for (int s = 0; s < 8; ++s) v += parts[(size_t)s * (256 * 4096) + idx];
    out[idx] = v;
}

extern "C" void kernel_launch(void* const* d_in, const int* in_sizes, int n_in,
                              void* d_out, int out_size, void* d_ws, size_t ws_size,
                              hipStream_t stream) {
    (void)in_sizes; (void)n_in; (void)out_size; (void)ws_size;
    const float* x   = (const float*)d_in[0];
    const int*   ei  = (const int*)d_in[1];
    const float* ea  = (const float*)d_in[2];
    /* d_in[3] = batch (unused, fixed layout) */
    const float* Wl  = (const float*)d_in[4];
    const float* Wr  = (const float*)d_in[5];
    const float* We  = (const float*)d_in[6];
    const float* att = (const float*)d_in[7];
    const float* bg  = (const float*)d_in[8];
    const float* W   = (const float*)d_in[9];
    const float* lb  = (const float*)d_in[10];
    float* out = (float*)d_out;

    char* p = (char*)d_ws;
    float* xl           = (float*)p;          p += 16777216;           // 16384x256 f32
    float* xr           = (float*)p;          p += 16777216;
    unsigned short* hb  = (unsigned short*)p; p += 8388608;            // 16384x256 bf16
    float* parts        = (float*)p;          p += 33554432;           // 8x256x4096 f32
    float* eapart       = (float*)p;          p += 16384;              // 256x16
    float* eeself       = (float*)p;          p += 1024;               // 256

    k_ea_part  <<<256,  256, 0, stream>>>(ea, eapart);
    k_ea_finish<<<1,    256, 0, stream>>>(eapart, We, eeself);
    k_xlr2     <<<dim3(256, 4), 256, 0, stream>>>(x, Wl, Wr, xl, xr);
    k_attn     <<<1024, 256, 0, stream>>>(ei, ea, eeself, att, We, xl, xr, bg, hb);
    k_gemm     <<<dim3(64, 8), 256, 0, stream>>>(hb, W, parts);
    k_reduce   <<<4096, 256, 0, stream>>>(parts, lb, out);
}